// Round 7
// baseline (122.325 us; speedup 1.0000x reference)
//
#include <hip/hip_runtime.h>
#include <hip/hip_bf16.h>

typedef unsigned short u16;
typedef __bf16 bf16x8 __attribute__((ext_vector_type(8)));
typedef float f32x4 __attribute__((ext_vector_type(4)));

typedef const __attribute__((address_space(1))) void gv_t;
typedef __attribute__((address_space(3))) void lv_t;

#define NN 2048
#define DD 1024
#define SS 49
#define CC 1000
#define CP 1024

#define BK 64
#define KK DD
#define NT (KK / BK)   // 16 K-steps

__device__ inline u16 f2bf(float f) {
    __hip_bfloat16 h = __float2bfloat16(f);
    union { __hip_bfloat16 h; u16 u; } cv; cv.h = h; return cv.u;
}

// ---- 64x64 MFMA GEMM core: 3-buffer, 2-deep prefetch, counted vmcnt --------
// One raw s_barrier per K-step; s_waitcnt vmcnt(4) keeps the next tile's 4
// global_load_lds in flight across the barrier (T4 mechanism; never drain to
// 0 mid-loop). Buffer t+2 overwrites buffer t-1, whose readers all passed the
// iter-t top barrier; per-wave vmcnt(4) before the barrier guarantees buffer
// t's loads landed in every wave. XOR swizzle via pre-swizzled GLOBAL source
// (linear LDS dest, rule both-sides-or-neither) + same XOR on read.
// smem: 3 x 16KB (As 8KB + Bs 8KB per buffer). global_load_lds offset arg
// must be a LITERAL -> k0 folded into the pointer.
__device__ __forceinline__ void gemm64_core(const u16* __restrict__ A,
                                            const u16* __restrict__ Bt,
                                            int m0, int n0, char* smem,
                                            f32x4 acc[2][2], int tid) {
    const int lane = tid & 63;
    const int wr = (tid >> 6) >> 1, wc = (tid >> 6) & 1;
    const int r16 = lane & 15, hk = lane >> 4;
    const char* Ab = (const char*)A;
    const char* Bb = (const char*)Bt;

    auto stage = [&](int buf, int k0) {
        #pragma unroll
        for (int j = 0; j < 2; j++) {
            const int c = j * 256 + tid;
            const int row = c >> 3, slot = c & 7;
            const int goff = ((slot ^ (row & 7)) << 4);
            __builtin_amdgcn_global_load_lds(
                (gv_t*)(Ab + ((size_t)(m0 + row) * KK + k0) * 2 + goff),
                (lv_t*)(smem + buf * 16384 + c * 16), 16, 0, 0);
            __builtin_amdgcn_global_load_lds(
                (gv_t*)(Bb + ((size_t)(n0 + row) * KK + k0) * 2 + goff),
                (lv_t*)(smem + buf * 16384 + 8192 + c * 16), 16, 0, 0);
        }
    };

    stage(0, 0);
    stage(1, BK);
    for (int t = 0; t < NT; ++t) {
        if (t + 1 < NT) asm volatile("s_waitcnt vmcnt(4)" ::: "memory");
        else            asm volatile("s_waitcnt vmcnt(0)" ::: "memory");
        __builtin_amdgcn_s_barrier();
        __builtin_amdgcn_sched_barrier(0);
        if (t + 2 < NT) stage((t + 2) % 3, (t + 2) * BK);

        const char* As = smem + (t % 3) * 16384;
        const char* Bs = As + 8192;
        bf16x8 a[2][2], b[2][2];
        #pragma unroll
        for (int mi = 0; mi < 2; mi++) {
            const int row = wr * 32 + mi * 16 + r16;
            #pragma unroll
            for (int kk2 = 0; kk2 < 2; kk2++) {
                const int g = kk2 * 4 + hk;
                a[mi][kk2] = *(const bf16x8*)(As + row * 128 + ((g ^ (row & 7)) << 4));
            }
        }
        #pragma unroll
        for (int ni = 0; ni < 2; ni++) {
            const int row = wc * 32 + ni * 16 + r16;
            #pragma unroll
            for (int kk2 = 0; kk2 < 2; kk2++) {
                const int g = kk2 * 4 + hk;
                b[ni][kk2] = *(const bf16x8*)(Bs + row * 128 + ((g ^ (row & 7)) << 4));
            }
        }
        #pragma unroll
        for (int kk2 = 0; kk2 < 2; kk2++)
            #pragma unroll
            for (int mi = 0; mi < 2; mi++)
                #pragma unroll
                for (int ni = 0; ni < 2; ni++)
                    acc[mi][ni] = __builtin_amdgcn_mfma_f32_16x16x32_bf16(
                        a[mi][kk2], b[ni][kk2], acc[mi][ni], 0, 0, 0);
    }
}

// ---- epilogue helpers ------------------------------------------------------
// C/D layout col=lane&15, row=(lane>>4)*4+r  [verified m89/m91]

// pool one unit: z rows for 256 (n,d) pairs, LDS-staged coalesced float4.
__device__ __forceinline__ void pool_unit(const float* __restrict__ x, int u,
                                          float* __restrict__ zf,
                                          u16* __restrict__ zb,
                                          char* smem, int tid) {
    float* lds = (float*)smem;
    const size_t base = (size_t)u * (256 * SS);
    const float4* src = (const float4*)(x + base);
    float4* dst = (float4*)lds;
    #pragma unroll
    for (int i = 0; i < 13; i++) {
        int idx = i * 256 + tid;
        if (idx < (256 * SS) / 4) dst[idx] = src[idx];
    }
    __syncthreads();
    const float* r = lds + tid * SS;
    float s = 0.f;
    #pragma unroll
    for (int j = 0; j < SS; j++) s += r[j];
    s *= (1.f / 49.f);
    size_t o = (size_t)u * 256 + tid;
    zf[o] = s;
    zb[o] = f2bf(s);
}

// zQ-diag tile: qzh[row] += 0.25 * sum_gc (z x Q)[row,gc] * zf[row,gc]
__device__ __forceinline__ void zqd_epi(const f32x4 acc[2][2], int m0, int n0,
                                        const float* __restrict__ zf,
                                        float* __restrict__ qzh, int tid) {
    const int lane = tid & 63;
    const int wr = (tid >> 6) >> 1, wc = (tid >> 6) & 1;
    const int cr = (lane >> 4) * 4, cc2 = lane & 15;
    #pragma unroll
    for (int mi = 0; mi < 2; mi++) {
        const int gr0 = m0 + wr * 32 + mi * 16 + cr;
        #pragma unroll
        for (int r = 0; r < 4; r++) {
            const int row = gr0 + r;
            float v = 0.f;
            #pragma unroll
            for (int ni = 0; ni < 2; ni++) {
                const int gc = n0 + wc * 32 + ni * 16 + cc2;
                v += acc[mi][ni][r] * zf[(size_t)row * DD + gc];
            }
            #pragma unroll
            for (int m = 1; m < 16; m <<= 1) v += __shfl_xor(v, m);
            if (cc2 == 0) atomicAdd(qzh + row, 0.25f * v);
        }
    }
}

// score tile: out[row, gc] = 0.5*acc - qzh[row] - qmuh[gc], gc < CC
__device__ __forceinline__ void score_epi(const f32x4 acc[2][2], int m0, int n0,
                                          const float* __restrict__ qzh,
                                          const float* __restrict__ qmuh,
                                          float* __restrict__ out, int tid) {
    const int lane = tid & 63;
    const int wr = (tid >> 6) >> 1, wc = (tid >> 6) & 1;
    const int cr = (lane >> 4) * 4, cc2 = lane & 15;
    #pragma unroll
    for (int mi = 0; mi < 2; mi++) {
        #pragma unroll
        for (int ni = 0; ni < 2; ni++) {
            const int gr = m0 + wr * 32 + mi * 16 + cr;
            const int gc = n0 + wc * 32 + ni * 16 + cc2;
            if (gc < CC) {
                const float qm = qmuh[gc];
                #pragma unroll
                for (int r = 0; r < 4; r++)
                    out[(size_t)(gr + r) * CC + gc] =
                        0.5f * acc[mi][ni][r] - qzh[gr + r] - qm;
            }
        }
    }
}

// ---- L1a: prep (4096 blocks) + pool rows [0,1024) (4096 blocks) ------------
__global__ __launch_bounds__(256) void l1a_k(const float* __restrict__ x,
                                             const float* __restrict__ P,
                                             const float* __restrict__ mu,
                                             u16* __restrict__ q,
                                             u16* __restrict__ mu_bf,
                                             float* __restrict__ zf,
                                             u16* __restrict__ zb,
                                             float* __restrict__ qzh,
                                             float* __restrict__ qmuh) {
    __shared__ char smem[50176];
    const int tid = threadIdx.x, bid = blockIdx.x;
    if (bid < 4096) {   // prep
        int i = bid * 256 + tid;           // 0 .. DD*DD-1
        int r = i >> 10, c = i & 1023;
        q[i]     = f2bf(P[i] + P[c * DD + r]);
        mu_bf[i] = f2bf(r < CC ? mu[i] : 0.f);
        if (i < NN) qzh[i]  = 0.f;
        if (i < CP) qmuh[i] = 0.f;
    } else {            // pool units 0..4095 (rows 0..1023)
        pool_unit(x, bid - 4096, zf, zb, smem, tid);
    }
}

// ---- L1b: muQ (256) + zQd h0 (256) + pool rows [1024,2048) (4096) ----------
__global__ __launch_bounds__(256) void l1b_k(const float* __restrict__ x,
                                             const u16* __restrict__ q,
                                             const u16* __restrict__ mu_bf,
                                             const float* __restrict__ mu,
                                             const u16* __restrict__ z_bf,
                                             u16* __restrict__ b_bf,
                                             float* __restrict__ qmuh,
                                             const float* __restrict__ zf,
                                             float* __restrict__ zf_w,
                                             u16* __restrict__ zb_w,
                                             float* __restrict__ qzh) {
    __shared__ char smem[50176];
    const int tid = threadIdx.x, bid = blockIdx.x;
    if (bid < 256) {
        // muQ tile -> b_bf + qmuh
        const int m0 = (bid >> 4) * 64, n0 = (bid & 15) * 64;
        f32x4 acc[2][2] = {};
        gemm64_core(mu_bf, q, m0, n0, smem, acc, tid);
        const int lane = tid & 63;
        const int wr = (tid >> 6) >> 1, wc = (tid >> 6) & 1;
        const int cr = (lane >> 4) * 4, cc2 = lane & 15;
        #pragma unroll
        for (int mi = 0; mi < 2; mi++) {
            const int gr0 = m0 + wr * 32 + mi * 16 + cr;
            #pragma unroll
            for (int r = 0; r < 4; r++) {
                const int row = gr0 + r;
                float v = 0.f;
                #pragma unroll
                for (int ni = 0; ni < 2; ni++) {
                    const int gc = n0 + wc * 32 + ni * 16 + cc2;
                    float av = acc[mi][ni][r];
                    float sv = (row < CC) ? mu[(size_t)row * DD + gc] : 0.f;
                    v += av * sv;
                    b_bf[(size_t)row * DD + gc] = f2bf(av);
                }
                #pragma unroll
                for (int m = 1; m < 16; m <<= 1) v += __shfl_xor(v, m);
                if (cc2 == 0) atomicAdd(qmuh + row, 0.25f * v);
            }
        }
    } else if (bid < 512) {
        // zQ-diag tile, rows [0,1024)
        const int i = bid - 256;
        const int m0 = (i >> 4) * 64, n0 = (i & 15) * 64;
        f32x4 acc[2][2] = {};
        gemm64_core(z_bf, q, m0, n0, smem, acc, tid);
        zqd_epi(acc, m0, n0, zf, qzh, tid);
    } else {
        // pool units 4096..8191 (rows 1024..2047)
        pool_unit(x, bid - 512 + 4096, zf_w, zb_w, smem, tid);
    }
}

// ---- L2: zQd h1 (256) + score h0 (256) --------------------------------------
__global__ __launch_bounds__(256) void l2_k(const u16* __restrict__ z_bf,
                                            const u16* __restrict__ q,
                                            const u16* __restrict__ b_bf,
                                            const float* __restrict__ zf,
                                            float* __restrict__ qzh,
                                            const float* __restrict__ qmuh,
                                            float* __restrict__ out) {
    __shared__ char smem[49152];
    const int tid = threadIdx.x, bid = blockIdx.x;
    if (bid < 256) {
        const int m0 = 1024 + (bid >> 4) * 64, n0 = (bid & 15) * 64;
        f32x4 acc[2][2] = {};
        gemm64_core(z_bf, q, m0, n0, smem, acc, tid);
        zqd_epi(acc, m0, n0, zf, qzh, tid);
    } else {
        const int i = bid - 256;
        const int m0 = (i >> 4) * 64, n0 = (i & 15) * 64;
        f32x4 acc[2][2] = {};
        gemm64_core(z_bf, b_bf, m0, n0, smem, acc, tid);
        score_epi(acc, m0, n0, qzh, qmuh, out, tid);
    }
}

// ---- L3: score h1 (256) ------------------------------------------------------
__global__ __launch_bounds__(256) void l3_k(const u16* __restrict__ z_bf,
                                            const u16* __restrict__ b_bf,
                                            const float* __restrict__ qzh,
                                            const float* __restrict__ qmuh,
                                            float* __restrict__ out) {
    __shared__ char smem[49152];
    const int tid = threadIdx.x, bid = blockIdx.x;
    const int m0 = 1024 + (bid >> 4) * 64, n0 = (bid & 15) * 64;
    f32x4 acc[2][2] = {};
    gemm64_core(z_bf, b_bf, m0, n0, smem, acc, tid);
    score_epi(acc, m0, n0, qzh, qmuh, out, tid);
}

extern "C" void kernel_launch(void* const* d_in, const int* in_sizes, int n_in,
                              void* d_out, int out_size, void* d_ws, size_t ws_size,
                              hipStream_t stream) {
    const float* x  = (const float*)d_in[0];   // [N, D, S]
    const float* mu = (const float*)d_in[1];   // [C, D]
    const float* P  = (const float*)d_in[2];   // [D, D]
    float* out = (float*)d_out;                // [N, C]

    // workspace carve (~18.3 MB)
    char* w = (char*)d_ws;
    u16*   q_bf  = (u16*)w;   w += (size_t)DD * DD * 2;   // 2 MB
    u16*   mu_bf = (u16*)w;   w += (size_t)CP * DD * 2;   // 2 MB
    u16*   b_bf  = (u16*)w;   w += (size_t)CP * DD * 2;   // 2 MB
    u16*   z_bf  = (u16*)w;   w += (size_t)NN * DD * 2;   // 4 MB
    float* zf    = (float*)w; w += (size_t)NN * DD * 4;   // 8 MB
    float* qzh   = (float*)w; w += (size_t)NN * 4;
    float* qmuh  = (float*)w;

    // L1a: prep + pool rows [0,1024)
    l1a_k<<<8192, 256, 0, stream>>>(x, P, mu, q_bf, mu_bf, zf, z_bf, qzh, qmuh);
    // L1b: muQ + zQ-diag(h0) hidden under pool rows [1024,2048)
    l1b_k<<<4608, 256, 0, stream>>>(x, q_bf, mu_bf, mu, z_bf, b_bf, qmuh,
                                    zf, zf, z_bf, qzh);
    // L2: zQ-diag(h1) + score(h0) -> out rows [0,1024)
    l2_k<<<512, 256, 0, stream>>>(z_bf, q_bf, b_bf, zf, qzh, qmuh, out);
    // L3: score(h1) -> out rows [1024,2048)
    l3_k<<<256, 256, 0, stream>>>(z_bf, b_bf, qzh, qmuh, out);
}

// Round 8
// 120.141 us; speedup vs baseline: 1.0182x; 1.0182x over previous
//
#include <hip/hip_runtime.h>
#include <hip/hip_bf16.h>

typedef unsigned short u16;
typedef __bf16 bf16x8 __attribute__((ext_vector_type(8)));
typedef float f32x4 __attribute__((ext_vector_type(4)));

typedef const __attribute__((address_space(1))) void gv_t;
typedef __attribute__((address_space(3))) void lv_t;

#define NN 2048
#define DD 1024
#define SS 49
#define CC 1000
#define CP 1024

#define BK 64
#define KK DD
#define NT (KK / BK)   // 16 K-steps

// pool geometry: half-unit = 128 rows x 49 floats = 25088 B
#define HALF_BYTES  25088
#define HALF_CHUNKS 1568           // 16B chunks per half-unit
#define N_HALVES    ((NN * DD) / 128)   // 16384
#define POOL_BLKS   768

__device__ inline u16 f2bf(float f) {
    __hip_bfloat16 h = __float2bfloat16(f);
    union { __hip_bfloat16 h; u16 u; } cv; cv.h = h; return cv.u;
}

// ---- 64x64 MFMA GEMM core: 3-buffer, 2-deep prefetch, counted vmcnt --------
// (r7 core, verified absmax 8) One raw s_barrier per K-step; vmcnt(4) keeps
// next tile's 4 global_load_lds in flight across the barrier. XOR swizzle via
// pre-swizzled GLOBAL source (linear LDS dest) + same XOR on read.
__device__ __forceinline__ void gemm64_core(const u16* __restrict__ A,
                                            const u16* __restrict__ Bt,
                                            int m0, int n0, char* smem,
                                            f32x4 acc[2][2], int tid) {
    const int lane = tid & 63;
    const int wr = (tid >> 6) >> 1, wc = (tid >> 6) & 1;
    const int r16 = lane & 15, hk = lane >> 4;
    const char* Ab = (const char*)A;
    const char* Bb = (const char*)Bt;

    auto stage = [&](int buf, int k0) {
        #pragma unroll
        for (int j = 0; j < 2; j++) {
            const int c = j * 256 + tid;
            const int row = c >> 3, slot = c & 7;
            const int goff = ((slot ^ (row & 7)) << 4);
            __builtin_amdgcn_global_load_lds(
                (gv_t*)(Ab + ((size_t)(m0 + row) * KK + k0) * 2 + goff),
                (lv_t*)(smem + buf * 16384 + c * 16), 16, 0, 0);
            __builtin_amdgcn_global_load_lds(
                (gv_t*)(Bb + ((size_t)(n0 + row) * KK + k0) * 2 + goff),
                (lv_t*)(smem + buf * 16384 + 8192 + c * 16), 16, 0, 0);
        }
    };

    stage(0, 0);
    stage(1, BK);
    for (int t = 0; t < NT; ++t) {
        if (t + 1 < NT) asm volatile("s_waitcnt vmcnt(4)" ::: "memory");
        else            asm volatile("s_waitcnt vmcnt(0)" ::: "memory");
        __builtin_amdgcn_s_barrier();
        __builtin_amdgcn_sched_barrier(0);
        if (t + 2 < NT) stage((t + 2) % 3, (t + 2) * BK);

        const char* As = smem + (t % 3) * 16384;
        const char* Bs = As + 8192;
        bf16x8 a[2][2], b[2][2];
        #pragma unroll
        for (int mi = 0; mi < 2; mi++) {
            const int row = wr * 32 + mi * 16 + r16;
            #pragma unroll
            for (int kk2 = 0; kk2 < 2; kk2++) {
                const int g = kk2 * 4 + hk;
                a[mi][kk2] = *(const bf16x8*)(As + row * 128 + ((g ^ (row & 7)) << 4));
            }
        }
        #pragma unroll
        for (int ni = 0; ni < 2; ni++) {
            const int row = wc * 32 + ni * 16 + r16;
            #pragma unroll
            for (int kk2 = 0; kk2 < 2; kk2++) {
                const int g = kk2 * 4 + hk;
                b[ni][kk2] = *(const bf16x8*)(Bs + row * 128 + ((g ^ (row & 7)) << 4));
            }
        }
        #pragma unroll
        for (int kk2 = 0; kk2 < 2; kk2++)
            #pragma unroll
            for (int mi = 0; mi < 2; mi++)
                #pragma unroll
                for (int ni = 0; ni < 2; ni++)
                    acc[mi][ni] = __builtin_amdgcn_mfma_f32_16x16x32_bf16(
                        a[mi][kk2], b[ni][kk2], acc[mi][ni], 0, 0, 0);
    }
}

// ---- L0: prep. q = bf16(P+P^T); mu_bf zero-padded; zero qzh/qmuh. ----------
__global__ __launch_bounds__(256) void prep_k(const float* __restrict__ P,
                                              const float* __restrict__ mu,
                                              u16* __restrict__ q,
                                              u16* __restrict__ mu_bf,
                                              float* __restrict__ qzh,
                                              float* __restrict__ qmuh) {
    int i = blockIdx.x * 256 + threadIdx.x;      // 0 .. DD*DD-1
    int r = i >> 10, c = i & 1023;
    q[i]     = f2bf(P[i] + P[c * DD + r]);
    mu_bf[i] = f2bf(r < CC ? mu[i] : 0.f);
    if (i < NN) qzh[i]  = 0.f;
    if (i < CP) qmuh[i] = 0.f;
}

// ---- L1: muQ GEMM (256 blocks, first) + pipelined pool (768 persistent) ----
// Pool: per iteration issue next half-unit's 7 global_load_lds BEFORE the
// reduce so HBM loads stay in flight through the reduce phase. vmcnt(0) sits
// where only the CURRENT buffer's loads are outstanding (next not yet
// issued), so it is an exact "current done" wait, not a pipeline drain.
__global__ __launch_bounds__(256) void pool_muq_k(const float* __restrict__ x,
                                                  const u16* __restrict__ q,
                                                  const u16* __restrict__ mu_bf,
                                                  const float* __restrict__ mu,
                                                  u16* __restrict__ b_bf,
                                                  float* __restrict__ qmuh,
                                                  float* __restrict__ zf,
                                                  u16* __restrict__ zb) {
    __shared__ char smem[50176];   // pool: 2 x 25088 dbuf; gemm: 3 x 16K
    const int tid = threadIdx.x;
    const int bid = blockIdx.x;

    if (bid >= 256) {
        // ---------------- pipelined pool ----------------
        const int pb = bid - 256;              // 0..767
        char* bufA = smem;
        char* bufB = smem + HALF_BYTES;
        const char* xb = (const char*)x;

        auto issue = [&](char* buf, int H) {
            const char* src = xb + (size_t)H * HALF_BYTES;
            #pragma unroll
            for (int i = 0; i < 7; i++) {
                const int c = i * 256 + tid;
                if (c < HALF_CHUNKS)
                    __builtin_amdgcn_global_load_lds(
                        (gv_t*)(src + c * 16), (lv_t*)(buf + c * 16), 16, 0, 0);
            }
        };

        int H = pb;
        char* cur = bufA;
        char* nxt = bufB;
        issue(cur, H);
        while (H < N_HALVES) {
            asm volatile("s_waitcnt vmcnt(0)" ::: "memory");  // current landed
            __builtin_amdgcn_s_barrier();                     // visible to all
            __builtin_amdgcn_sched_barrier(0);
            const int Hn = H + POOL_BLKS;
            if (Hn < N_HALVES) issue(nxt, Hn);                // prefetch next
            if (tid < 128) {                                  // reduce current
                const float* row = (const float*)cur + tid * SS;
                float s = 0.f;
                #pragma unroll
                for (int j = 0; j < SS; j++) s += row[j];
                s *= (1.f / 49.f);
                const size_t o = (size_t)H * 128 + tid;
                zf[o] = s;
                zb[o] = f2bf(s);
            }
            char* t_ = cur; cur = nxt; nxt = t_;
            H = Hn;
        }
        return;
    }

    // ---------------- muQ GEMM tile (b_bf + qmuh) ----------------
    const int m0 = (bid >> 4) * 64, n0 = (bid & 15) * 64;
    f32x4 acc[2][2] = {};
    gemm64_core(mu_bf, q, m0, n0, smem, acc, tid);

    const int lane = tid & 63;
    const int wr = (tid >> 6) >> 1, wc = (tid >> 6) & 1;
    const int cr = (lane >> 4) * 4, cc2 = lane & 15;
    #pragma unroll
    for (int mi = 0; mi < 2; mi++) {
        const int gr0 = m0 + wr * 32 + mi * 16 + cr;
        #pragma unroll
        for (int r = 0; r < 4; r++) {
            const int row = gr0 + r;
            float v = 0.f;
            #pragma unroll
            for (int ni = 0; ni < 2; ni++) {
                const int gc = n0 + wc * 32 + ni * 16 + cc2;
                float av = acc[mi][ni][r];
                float sv = (row < CC) ? mu[(size_t)row * DD + gc] : 0.f;
                v += av * sv;
                b_bf[(size_t)row * DD + gc] = f2bf(av);
            }
            #pragma unroll
            for (int m = 1; m < 16; m <<= 1) v += __shfl_xor(v, m);
            if (cc2 == 0) atomicAdd(qmuh + row, 0.25f * v);
        }
    }
}

// ---- L2: zQ-diag (512, bid<512) + score-partial (512) ----------------------
// score writes out[n,c] = 0.5*acc - qmuh[c] (qzh subtracted by L3 fixup, so
// score does not depend on zQ-diag -> both roles fully parallel).
__global__ __launch_bounds__(256) void zgemm_k(const u16* __restrict__ z_bf,
                                               const u16* __restrict__ q,
                                               const u16* __restrict__ b_bf,
                                               const float* __restrict__ zf,
                                               float* __restrict__ qzh,
                                               const float* __restrict__ qmuh,
                                               float* __restrict__ out) {
    __shared__ char smem[49152];
    const int tid = threadIdx.x;
    const int bid = blockIdx.x;
    const int lane = tid & 63;
    const int wr = (tid >> 6) >> 1, wc = (tid >> 6) & 1;
    const int cr = (lane >> 4) * 4, cc2 = lane & 15;

    if (bid < 512) {
        // zQ-diag tile: qzh[row] += 0.25 * sum_gc (zQ)[row,gc] * zf[row,gc]
        const int m0 = (bid >> 4) * 64, n0 = (bid & 15) * 64;
        f32x4 acc[2][2] = {};
        gemm64_core(z_bf, q, m0, n0, smem, acc, tid);
        #pragma unroll
        for (int mi = 0; mi < 2; mi++) {
            const int gr0 = m0 + wr * 32 + mi * 16 + cr;
            #pragma unroll
            for (int r = 0; r < 4; r++) {
                const int row = gr0 + r;
                float v = 0.f;
                #pragma unroll
                for (int ni = 0; ni < 2; ni++) {
                    const int gc = n0 + wc * 32 + ni * 16 + cc2;
                    v += acc[mi][ni][r] * zf[(size_t)row * DD + gc];
                }
                #pragma unroll
                for (int m = 1; m < 16; m <<= 1) v += __shfl_xor(v, m);
                if (cc2 == 0) atomicAdd(qzh + row, 0.25f * v);
            }
        }
    } else {
        // score tile
        const int i = bid - 512;
        const int m0 = (i >> 4) * 64, n0 = (i & 15) * 64;
        f32x4 acc[2][2] = {};
        gemm64_core(z_bf, b_bf, m0, n0, smem, acc, tid);
        #pragma unroll
        for (int mi = 0; mi < 2; mi++) {
            #pragma unroll
            for (int ni = 0; ni < 2; ni++) {
                const int gr = m0 + wr * 32 + mi * 16 + cr;
                const int gc = n0 + wc * 32 + ni * 16 + cc2;
                if (gc < CC) {
                    const float qm = qmuh[gc];
                    #pragma unroll
                    for (int r = 0; r < 4; r++)
                        out[(size_t)(gr + r) * CC + gc] =
                            0.5f * acc[mi][ni][r] - qm;
                }
            }
        }
    }
}

// ---- L3: in-place fixup out[n,c] -= qzh[n] ---------------------------------
__global__ __launch_bounds__(256) void fixup_k(float* __restrict__ out,
                                               const float* __restrict__ qzh) {
    const int n = blockIdx.x, tid = threadIdx.x;
    if (tid >= 250) return;
    const float qz = qzh[n];
    float4* p = (float4*)(out + (size_t)n * CC + tid * 4);
    float4 v = *p;
    v.x -= qz; v.y -= qz; v.z -= qz; v.w -= qz;
    *p = v;
}

extern "C" void kernel_launch(void* const* d_in, const int* in_sizes, int n_in,
                              void* d_out, int out_size, void* d_ws, size_t ws_size,
                              hipStream_t stream) {
    const float* x  = (const float*)d_in[0];   // [N, D, S]
    const float* mu = (const float*)d_in[1];   // [C, D]
    const float* P  = (const float*)d_in[2];   // [D, D]
    float* out = (float*)d_out;                // [N, C]

    // workspace carve (~18.3 MB)
    char* w = (char*)d_ws;
    u16*   q_bf  = (u16*)w;   w += (size_t)DD * DD * 2;   // 2 MB
    u16*   mu_bf = (u16*)w;   w += (size_t)CP * DD * 2;   // 2 MB
    u16*   b_bf  = (u16*)w;   w += (size_t)CP * DD * 2;   // 2 MB
    u16*   z_bf  = (u16*)w;   w += (size_t)NN * DD * 2;   // 4 MB
    float* zf    = (float*)w; w += (size_t)NN * DD * 4;   // 8 MB
    float* qzh   = (float*)w; w += (size_t)NN * 4;
    float* qmuh  = (float*)w;

    // L0: prep (q, mu_bf, zero accumulators)
    prep_k<<<(DD * DD) / 256, 256, 0, stream>>>(P, mu, q_bf, mu_bf, qzh, qmuh);
    // L1: muQ (256 first) + pipelined persistent pool (768)
    pool_muq_k<<<256 + POOL_BLKS, 256, 0, stream>>>(
        x, q_bf, mu_bf, mu, b_bf, qmuh, zf, z_bf);
    // L2: zQ-diag (512) + score-partial (512) -> out (minus qmuh only)
    zgemm_k<<<1024, 256, 0, stream>>>(z_bf, q_bf, b_bf, zf, qzh, qmuh, out);
    // L3: out[n,:] -= qzh[n] in place
    fixup_k<<<NN, 256, 0, stream>>>(out, qzh);
}